// Round 1
// baseline (162.129 us; speedup 1.0000x reference)
//
#include <hip/hip_runtime.h>

// GAT: N=4096, F_IN=128, F_HID=64, H=4, F_OUT=64, alpha=0.2
#define GN 4096
#define F_IN 128
#define F_HID 64
#define NHEADS 4
#define F_OUT 64
#define ALPHA 0.2f
#define MAX_DEG 256

// ---------------- workspace layout (bytes) ----------------
// h      : GN*F_IN*4          = 2,097,152   @ 0
// Wh_all : GN*256*4           = 4,194,304   @ 2,097,152   layout [i][head][f]
// src1   : NHEADS*GN*4        = 65,536      @ 6,291,456   [head*GN + i]
// dst1   : NHEADS*GN*4        = 65,536      @ 6,356,992
// hcat   : GN*256*4           = 4,194,304   @ 6,422,528   [i][head*64+f]
// Wh2    : GN*64*4            = 1,048,576   @ 10,616,832
// src2   : GN*4               = 16,384      @ 11,665,408
// dst2   : GN*4               = 16,384      @ 11,681,792
// cnt    : GN*4               = 16,384      @ 11,698,176
// idx    : GN*MAX_DEG*4       = 4,194,304   @ 11,714,560
// total ~15.2 MB

#define OFF_H      0
#define OFF_WH     2097152
#define OFF_SRC1   6291456
#define OFF_DST1   6356992
#define OFF_HCAT   6422528
#define OFF_WH2    10616832
#define OFF_SRC2   11665408
#define OFF_DST2   11681792
#define OFF_CNT    11698176
#define OFF_IDX    11714560

// --------- deterministic neighbor-list compaction (ascending j) ---------
// one 64-lane wave per row; 4 waves per 256-thread block
__global__ void build_nbr_kernel(const float* __restrict__ adj,
                                 int* __restrict__ cnt, int* __restrict__ idx) {
    const int wave = threadIdx.x >> 6;
    const int lane = threadIdx.x & 63;
    const int row  = blockIdx.x * 4 + wave;
    if (row >= GN) return;
    const float* arow = adj + (size_t)row * GN;
    int* out = idx + (size_t)row * MAX_DEG;
    int count = 0;
    for (int base = 0; base < GN; base += 64) {
        float v = arow[base + lane];
        bool nz = (v > 0.0f);
        unsigned long long m = __ballot(nz);
        if (nz) {
            int p = __popcll(m & ((1ULL << lane) - 1ULL));
            int pos = count + p;
            if (pos < MAX_DEG) out[pos] = base + lane;
        }
        count += __popcll(m);
    }
    if (lane == 0) cnt[row] = (count > MAX_DEG) ? MAX_DEG : count;
}

// --------- h = x @ lin_W + b   (one thread per output elem) ---------
__global__ void lin_kernel(const float* __restrict__ x, const float* __restrict__ W,
                           const float* __restrict__ b, float* __restrict__ h) {
    int t = blockIdx.x * blockDim.x + threadIdx.x;     // over GN*F_IN
    int i = t >> 7, k = t & 127;
    const float* xr = x + (size_t)i * F_IN;
    float acc = b[k];
    #pragma unroll 8
    for (int j = 0; j < F_IN; ++j) acc += xr[j] * W[j * F_IN + k];
    h[t] = acc;
}

// --------- Wh_all[i][head][f] = h[i,:] @ W_heads[head][:,f] ---------
__global__ void wh_kernel(const float* __restrict__ h, const float* __restrict__ Wheads,
                          float* __restrict__ Wh) {
    int t = blockIdx.x * blockDim.x + threadIdx.x;     // over GN*256
    int i = t >> 8, c = t & 255;
    int hd = c >> 6, f = c & 63;
    const float* hr = h + (size_t)i * F_IN;
    const float* W  = Wheads + (size_t)hd * F_IN * F_HID + f;
    float acc = 0.0f;
    #pragma unroll 8
    for (int j = 0; j < F_IN; ++j) acc += hr[j] * W[j * F_HID];
    Wh[t] = acc;
}

// --------- src/dst projections for layer 1 ---------
__global__ void srcdst1_kernel(const float* __restrict__ Wh, const float* __restrict__ a,
                               float* __restrict__ src, float* __restrict__ dst) {
    int t = blockIdx.x * blockDim.x + threadIdx.x;     // over NHEADS*GN
    if (t >= NHEADS * GN) return;
    int hd = t >> 12, i = t & (GN - 1);
    const float* w  = Wh + (size_t)i * 256 + hd * 64;
    const float* ah = a + hd * 2 * F_HID;
    float s = 0.0f, d = 0.0f;
    #pragma unroll 8
    for (int f = 0; f < F_HID; ++f) { s += w[f] * ah[f]; d += w[f] * ah[F_HID + f]; }
    src[t] = s; dst[t] = d;
}

// --------- layer-1 attention: one wave per (row, head); lane = feature ---------
__global__ void attn1_kernel(const float* __restrict__ Wh, const float* __restrict__ src,
                             const float* __restrict__ dst, const int* __restrict__ cnt,
                             const int* __restrict__ idx, float* __restrict__ hcat) {
    const int hd   = threadIdx.x >> 6;   // wave id = head
    const int lane = threadIdx.x & 63;   // feature
    const int row  = blockIdx.x;
    const int deg  = cnt[row];
    const int* nb  = idx + (size_t)row * MAX_DEG;
    const float s_i = src[hd * GN + row];
    float m = -1e30f, l = 0.0f, acc = 0.0f;
    for (int t = 0; t < deg; ++t) {
        int j = nb[t];
        float e = s_i + dst[hd * GN + j];
        e = (e > 0.0f) ? e : ALPHA * e;
        float mn = fmaxf(m, e);
        float scale = expf(m - mn);
        float p = expf(e - mn);
        l = l * scale + p;
        acc = acc * scale + p * Wh[(size_t)j * 256 + hd * 64 + lane];
        m = mn;
    }
    float v = acc / l;
    v = (v > 0.0f) ? v : expm1f(v);      // elu
    hcat[(size_t)row * 256 + hd * 64 + lane] = v;
}

// --------- Wh2 = hcat @ W_end ---------
__global__ void wh2_kernel(const float* __restrict__ hcat, const float* __restrict__ Wend,
                           float* __restrict__ Wh2) {
    int t = blockIdx.x * blockDim.x + threadIdx.x;     // over GN*64
    int i = t >> 6, f = t & 63;
    const float* hr = hcat + (size_t)i * 256;
    const float* W  = Wend + f;
    float acc = 0.0f;
    #pragma unroll 8
    for (int j = 0; j < 256; ++j) acc += hr[j] * W[j * F_OUT];
    Wh2[t] = acc;
}

// --------- src/dst projections for layer 2 ---------
__global__ void srcdst2_kernel(const float* __restrict__ Wh2, const float* __restrict__ a,
                               float* __restrict__ src, float* __restrict__ dst) {
    int i = blockIdx.x * blockDim.x + threadIdx.x;     // over GN
    if (i >= GN) return;
    const float* w = Wh2 + (size_t)i * F_OUT;
    float s = 0.0f, d = 0.0f;
    #pragma unroll 8
    for (int f = 0; f < F_OUT; ++f) { s += w[f] * a[f]; d += w[f] * a[F_OUT + f]; }
    src[i] = s; dst[i] = d;
}

// --------- layer-2 attention + elu + final row softmax ---------
// one wave per row; 4 waves per block
__global__ void attn2_kernel(const float* __restrict__ Wh2, const float* __restrict__ src,
                             const float* __restrict__ dst, const int* __restrict__ cnt,
                             const int* __restrict__ idx, float* __restrict__ out) {
    const int wave = threadIdx.x >> 6;
    const int lane = threadIdx.x & 63;   // feature
    const int row  = blockIdx.x * 4 + wave;
    if (row >= GN) return;
    const int deg = cnt[row];
    const int* nb = idx + (size_t)row * MAX_DEG;
    const float s_i = src[row];
    float m = -1e30f, l = 0.0f, acc = 0.0f;
    for (int t = 0; t < deg; ++t) {
        int j = nb[t];
        float e = s_i + dst[j];
        e = (e > 0.0f) ? e : ALPHA * e;
        float mn = fmaxf(m, e);
        float scale = expf(m - mn);
        float p = expf(e - mn);
        l = l * scale + p;
        acc = acc * scale + p * Wh2[(size_t)j * F_OUT + lane];
        m = mn;
    }
    float v = acc / l;
    v = (v > 0.0f) ? v : expm1f(v);      // elu
    // final softmax across the 64 lanes (features)
    float mm = v;
    #pragma unroll
    for (int o = 32; o > 0; o >>= 1) mm = fmaxf(mm, __shfl_xor(mm, o, 64));
    float ee = expf(v - mm);
    float ss = ee;
    #pragma unroll
    for (int o = 32; o > 0; o >>= 1) ss += __shfl_xor(ss, o, 64);
    out[(size_t)row * F_OUT + lane] = ee / ss;
}

extern "C" void kernel_launch(void* const* d_in, const int* in_sizes, int n_in,
                              void* d_out, int out_size, void* d_ws, size_t ws_size,
                              hipStream_t stream) {
    const float* x      = (const float*)d_in[0];
    const float* adj    = (const float*)d_in[1];
    const float* lin_W  = (const float*)d_in[2];
    const float* lin_b  = (const float*)d_in[3];
    const float* Wheads = (const float*)d_in[4];
    const float* aheads = (const float*)d_in[5];
    const float* Wend   = (const float*)d_in[6];
    const float* aend   = (const float*)d_in[7];
    float* out = (float*)d_out;

    char* ws = (char*)d_ws;
    float* h    = (float*)(ws + OFF_H);
    float* Wh   = (float*)(ws + OFF_WH);
    float* src1 = (float*)(ws + OFF_SRC1);
    float* dst1 = (float*)(ws + OFF_DST1);
    float* hcat = (float*)(ws + OFF_HCAT);
    float* Wh2  = (float*)(ws + OFF_WH2);
    float* src2 = (float*)(ws + OFF_SRC2);
    float* dst2 = (float*)(ws + OFF_DST2);
    int*   cnt  = (int*)(ws + OFF_CNT);
    int*   nidx = (int*)(ws + OFF_IDX);

    // 1) neighbor compaction (reads adj once, 67 MB)
    build_nbr_kernel<<<GN / 4, 256, 0, stream>>>(adj, cnt, nidx);
    // 2) h = x @ lin_W + b
    lin_kernel<<<(GN * F_IN) / 256, 256, 0, stream>>>(x, lin_W, lin_b, h);
    // 3) Wh_all for all 4 heads
    wh_kernel<<<(GN * 256) / 256, 256, 0, stream>>>(h, Wheads, Wh);
    // 4) src/dst layer 1
    srcdst1_kernel<<<(NHEADS * GN) / 256, 256, 0, stream>>>(Wh, aheads, src1, dst1);
    // 5) layer-1 attention -> hcat
    attn1_kernel<<<GN, 256, 0, stream>>>(Wh, src1, dst1, cnt, nidx, hcat);
    // 6) Wh2 = hcat @ W_end
    wh2_kernel<<<(GN * F_OUT) / 256, 256, 0, stream>>>(hcat, Wend, Wh2);
    // 7) src/dst layer 2
    srcdst2_kernel<<<GN / 256, 256, 0, stream>>>(Wh2, aend, src2, dst2);
    // 8) layer-2 attention + final softmax
    attn2_kernel<<<GN / 4, 256, 0, stream>>>(Wh2, src2, dst2, cnt, nidx, out);
}

// Round 2
// 138.885 us; speedup vs baseline: 1.1674x; 1.1674x over previous
//
#include <hip/hip_runtime.h>

// GAT: N=4096, F_IN=128, F_HID=64, H=4, F_OUT=64, alpha=0.2
#define GN 4096
#define F_IN 128
#define F_HID 64
#define NHEADS 4
#define F_OUT 64
#define ALPHA 0.2f
#define MAX_DEG 256

#define OFF_H      0
#define OFF_WH     2097152
#define OFF_SRC1   6291456
#define OFF_DST1   6356992
#define OFF_HCAT   6422528
#define OFF_WH2    10616832
#define OFF_SRC2   11665408
#define OFF_DST2   11681792
#define OFF_CNT    11698176
#define OFF_IDX    11714560

// --------- deterministic neighbor-list compaction (ascending j), float4 ---------
// one 64-lane wave per row; 4 waves per 256-thread block. 16B/lane/iter.
__global__ void build_nbr_kernel(const float* __restrict__ adj,
                                 int* __restrict__ cnt, int* __restrict__ idx) {
    const int wave = threadIdx.x >> 6;
    const int lane = threadIdx.x & 63;
    const int row  = blockIdx.x * 4 + wave;
    if (row >= GN) return;
    const float4* a4 = (const float4*)(adj + (size_t)row * GN);
    int* out = idx + (size_t)row * MAX_DEG;
    const unsigned long long low = (lane == 0) ? 0ULL : ((1ULL << lane) - 1ULL);
    int count = 0;
    #pragma unroll 4
    for (int it = 0; it < GN / 256; ++it) {
        float4 v = a4[it * 64 + lane];
        bool b0 = v.x > 0.0f, b1 = v.y > 0.0f, b2 = v.z > 0.0f, b3 = v.w > 0.0f;
        unsigned long long m0 = __ballot(b0), m1 = __ballot(b1);
        unsigned long long m2 = __ballot(b2), m3 = __ballot(b3);
        int pos = count + __popcll(m0 & low) + __popcll(m1 & low)
                        + __popcll(m2 & low) + __popcll(m3 & low);
        int col = it * 256 + lane * 4;
        if (b0 && pos < MAX_DEG) out[pos] = col;     pos += b0;
        if (b1 && pos < MAX_DEG) out[pos] = col + 1; pos += b1;
        if (b2 && pos < MAX_DEG) out[pos] = col + 2; pos += b2;
        if (b3 && pos < MAX_DEG) out[pos] = col + 3; pos += b3;
        count += __popcll(m0) + __popcll(m1) + __popcll(m2) + __popcll(m3);
    }
    if (lane == 0) cnt[row] = (count > MAX_DEG) ? MAX_DEG : count;
}

// --------- h = x @ lin_W + b ---------
__global__ void lin_kernel(const float* __restrict__ x, const float* __restrict__ W,
                           const float* __restrict__ b, float* __restrict__ h) {
    int t = blockIdx.x * blockDim.x + threadIdx.x;
    int i = t >> 7, k = t & 127;
    const float* xr = x + (size_t)i * F_IN;
    float acc = b[k];
    #pragma unroll 8
    for (int j = 0; j < F_IN; ++j) acc += xr[j] * W[j * F_IN + k];
    h[t] = acc;
}

// --------- Wh_all[i][head][f] = h[i,:] @ W_heads[head][:,f] ---------
__global__ void wh_kernel(const float* __restrict__ h, const float* __restrict__ Wheads,
                          float* __restrict__ Wh) {
    int t = blockIdx.x * blockDim.x + threadIdx.x;
    int i = t >> 8, c = t & 255;
    int hd = c >> 6, f = c & 63;
    const float* hr = h + (size_t)i * F_IN;
    const float* W  = Wheads + (size_t)hd * F_IN * F_HID + f;
    float acc = 0.0f;
    #pragma unroll 8
    for (int j = 0; j < F_IN; ++j) acc += hr[j] * W[j * F_HID];
    Wh[t] = acc;
}

// --------- src/dst projections for layer 1 ---------
__global__ void srcdst1_kernel(const float* __restrict__ Wh, const float* __restrict__ a,
                               float* __restrict__ src, float* __restrict__ dst) {
    int t = blockIdx.x * blockDim.x + threadIdx.x;
    if (t >= NHEADS * GN) return;
    int hd = t >> 12, i = t & (GN - 1);
    const float* w  = Wh + (size_t)i * 256 + hd * 64;
    const float* ah = a + hd * 2 * F_HID;
    float s = 0.0f, d = 0.0f;
    #pragma unroll 8
    for (int f = 0; f < F_HID; ++f) { s += w[f] * ah[f]; d += w[f] * ah[F_HID + f]; }
    src[t] = s; dst[t] = d;
}

// --------- layer-1 attention: wave per (row, head); two-phase softmax ---------
__global__ void attn1_kernel(const float* __restrict__ Wh, const float* __restrict__ src,
                             const float* __restrict__ dst, const int* __restrict__ cnt,
                             const int* __restrict__ idx, float* __restrict__ hcat) {
    const int hd   = threadIdx.x >> 6;   // wave id = head
    const int lane = threadIdx.x & 63;
    const int row  = blockIdx.x;
    const int deg  = cnt[row];
    const int* nb  = idx + (size_t)row * MAX_DEG;
    const float s_i = src[hd * GN + row];

    // phase 1: lanes over neighbors -> e, max, p, sum
    float e[4];
    #pragma unroll
    for (int c = 0; c < 4; ++c) {
        int t = c * 64 + lane;
        float ev = -1e30f;
        if (t < deg) {
            int j = nb[t];
            ev = s_i + dst[hd * GN + j];
            ev = (ev > 0.0f) ? ev : ALPHA * ev;
        }
        e[c] = ev;
    }
    float m = fmaxf(fmaxf(e[0], e[1]), fmaxf(e[2], e[3]));
    #pragma unroll
    for (int o = 32; o > 0; o >>= 1) m = fmaxf(m, __shfl_xor(m, o, 64));
    float l = 0.0f;
    #pragma unroll
    for (int c = 0; c < 4; ++c) { e[c] = expf(e[c] - m); l += e[c]; }
    #pragma unroll
    for (int o = 32; o > 0; o >>= 1) l += __shfl_xor(l, o, 64);

    // phase 2: lanes over features; broadcast p_t via shuffle
    float acc = 0.0f;
    #pragma unroll
    for (int c = 0; c < 4; ++c) {
        int base = c * 64;
        if (base < deg) {
            int nmax = deg - base; if (nmax > 64) nmax = 64;
            for (int t = 0; t < nmax; ++t) {
                float pv = __shfl(e[c], t, 64);
                int j = nb[base + t];
                acc += pv * Wh[(size_t)j * 256 + hd * 64 + lane];
            }
        }
    }
    float v = acc / l;
    v = (v > 0.0f) ? v : expm1f(v);      // elu
    hcat[(size_t)row * 256 + hd * 64 + lane] = v;
}

// --------- Wh2 = hcat @ W_end ---------
__global__ void wh2_kernel(const float* __restrict__ hcat, const float* __restrict__ Wend,
                           float* __restrict__ Wh2) {
    int t = blockIdx.x * blockDim.x + threadIdx.x;
    int i = t >> 6, f = t & 63;
    const float* hr = hcat + (size_t)i * 256;
    const float* W  = Wend + f;
    float acc = 0.0f;
    #pragma unroll 8
    for (int j = 0; j < 256; ++j) acc += hr[j] * W[j * F_OUT];
    Wh2[t] = acc;
}

// --------- src/dst projections for layer 2 ---------
__global__ void srcdst2_kernel(const float* __restrict__ Wh2, const float* __restrict__ a,
                               float* __restrict__ src, float* __restrict__ dst) {
    int i = blockIdx.x * blockDim.x + threadIdx.x;
    if (i >= GN) return;
    const float* w = Wh2 + (size_t)i * F_OUT;
    float s = 0.0f, d = 0.0f;
    #pragma unroll 8
    for (int f = 0; f < F_OUT; ++f) { s += w[f] * a[f]; d += w[f] * a[F_OUT + f]; }
    src[i] = s; dst[i] = d;
}

// --------- layer-2 attention + elu + final row softmax; wave per row ---------
__global__ void attn2_kernel(const float* __restrict__ Wh2, const float* __restrict__ src,
                             const float* __restrict__ dst, const int* __restrict__ cnt,
                             const int* __restrict__ idx, float* __restrict__ out) {
    const int wave = threadIdx.x >> 6;
    const int lane = threadIdx.x & 63;
    const int row  = blockIdx.x * 4 + wave;
    if (row >= GN) return;
    const int deg = cnt[row];
    const int* nb = idx + (size_t)row * MAX_DEG;
    const float s_i = src[row];

    float e[4];
    #pragma unroll
    for (int c = 0; c < 4; ++c) {
        int t = c * 64 + lane;
        float ev = -1e30f;
        if (t < deg) {
            int j = nb[t];
            ev = s_i + dst[j];
            ev = (ev > 0.0f) ? ev : ALPHA * ev;
        }
        e[c] = ev;
    }
    float m = fmaxf(fmaxf(e[0], e[1]), fmaxf(e[2], e[3]));
    #pragma unroll
    for (int o = 32; o > 0; o >>= 1) m = fmaxf(m, __shfl_xor(m, o, 64));
    float l = 0.0f;
    #pragma unroll
    for (int c = 0; c < 4; ++c) { e[c] = expf(e[c] - m); l += e[c]; }
    #pragma unroll
    for (int o = 32; o > 0; o >>= 1) l += __shfl_xor(l, o, 64);

    float acc = 0.0f;
    #pragma unroll
    for (int c = 0; c < 4; ++c) {
        int base = c * 64;
        if (base < deg) {
            int nmax = deg - base; if (nmax > 64) nmax = 64;
            for (int t = 0; t < nmax; ++t) {
                float pv = __shfl(e[c], t, 64);
                int j = nb[base + t];
                acc += pv * Wh2[(size_t)j * F_OUT + lane];
            }
        }
    }
    float v = acc / l;
    v = (v > 0.0f) ? v : expm1f(v);      // elu

    // final softmax across 64 lanes (features)
    float mm = v;
    #pragma unroll
    for (int o = 32; o > 0; o >>= 1) mm = fmaxf(mm, __shfl_xor(mm, o, 64));
    float ee = expf(v - mm);
    float ss = ee;
    #pragma unroll
    for (int o = 32; o > 0; o >>= 1) ss += __shfl_xor(ss, o, 64);
    out[(size_t)row * F_OUT + lane] = ee / ss;
}

extern "C" void kernel_launch(void* const* d_in, const int* in_sizes, int n_in,
                              void* d_out, int out_size, void* d_ws, size_t ws_size,
                              hipStream_t stream) {
    const float* x      = (const float*)d_in[0];
    const float* adj    = (const float*)d_in[1];
    const float* lin_W  = (const float*)d_in[2];
    const float* lin_b  = (const float*)d_in[3];
    const float* Wheads = (const float*)d_in[4];
    const float* aheads = (const float*)d_in[5];
    const float* Wend   = (const float*)d_in[6];
    const float* aend   = (const float*)d_in[7];
    float* out = (float*)d_out;

    char* ws = (char*)d_ws;
    float* h    = (float*)(ws + OFF_H);
    float* Wh   = (float*)(ws + OFF_WH);
    float* src1 = (float*)(ws + OFF_SRC1);
    float* dst1 = (float*)(ws + OFF_DST1);
    float* hcat = (float*)(ws + OFF_HCAT);
    float* Wh2  = (float*)(ws + OFF_WH2);
    float* src2 = (float*)(ws + OFF_SRC2);
    float* dst2 = (float*)(ws + OFF_DST2);
    int*   cnt  = (int*)(ws + OFF_CNT);
    int*   nidx = (int*)(ws + OFF_IDX);

    build_nbr_kernel<<<GN / 4, 256, 0, stream>>>(adj, cnt, nidx);
    lin_kernel<<<(GN * F_IN) / 256, 256, 0, stream>>>(x, lin_W, lin_b, h);
    wh_kernel<<<(GN * 256) / 256, 256, 0, stream>>>(h, Wheads, Wh);
    srcdst1_kernel<<<(NHEADS * GN) / 256, 256, 0, stream>>>(Wh, aheads, src1, dst1);
    attn1_kernel<<<GN, 256, 0, stream>>>(Wh, src1, dst1, cnt, nidx, hcat);
    wh2_kernel<<<(GN * F_OUT) / 256, 256, 0, stream>>>(hcat, Wend, Wh2);
    srcdst2_kernel<<<GN / 256, 256, 0, stream>>>(Wh2, aend, src2, dst2);
    attn2_kernel<<<GN / 4, 256, 0, stream>>>(Wh2, src2, dst2, cnt, nidx, out);
}

// Round 3
// 71.162 us; speedup vs baseline: 2.2783x; 1.9517x over previous
//
#include <hip/hip_runtime.h>

// GAT: N=4096, F_IN=128, F_HID=64, H=4, F_OUT=64, alpha=0.2
#define GN 4096
#define F_IN 128
#define F_HID 64
#define NHEADS 4
#define F_OUT 64
#define ALPHA 0.2f
#define MAX_DEG 256

// workspace layout (bytes)
#define OFF_WH     0           // GN*256*4  = 4 MB   [i][head*64+f]
#define OFF_SRC1   4194304     // 4*GN*4
#define OFF_DST1   4259840     // 4*GN*4
#define OFF_HCAT   4325376     // GN*256*4  = 4 MB
#define OFF_WH2    8519680     // GN*64*4   = 1 MB
#define OFF_SRC2   9568256     // GN*4
#define OFF_DST2   9584640     // GN*4
#define OFF_CNT    9601024     // GN*4
#define OFF_IDX    9617408     // GN*MAX_DEG*4 = 4 MB

// --------- neighbor compaction (ascending j), float4, pad-to-4 ---------
__global__ void build_nbr_kernel(const float* __restrict__ adj,
                                 int* __restrict__ cnt, int* __restrict__ idx) {
    const int wave = threadIdx.x >> 6;
    const int lane = threadIdx.x & 63;
    const int row  = blockIdx.x * 4 + wave;
    if (row >= GN) return;
    const float4* a4 = (const float4*)(adj + (size_t)row * GN);
    int* out = idx + (size_t)row * MAX_DEG;
    const unsigned long long low = (lane == 0) ? 0ULL : ((1ULL << lane) - 1ULL);
    int count = 0;
    #pragma unroll 4
    for (int it = 0; it < GN / 256; ++it) {
        float4 v = a4[it * 64 + lane];
        bool b0 = v.x > 0.0f, b1 = v.y > 0.0f, b2 = v.z > 0.0f, b3 = v.w > 0.0f;
        unsigned long long m0 = __ballot(b0), m1 = __ballot(b1);
        unsigned long long m2 = __ballot(b2), m3 = __ballot(b3);
        int pos = count + __popcll(m0 & low) + __popcll(m1 & low)
                        + __popcll(m2 & low) + __popcll(m3 & low);
        int col = it * 256 + lane * 4;
        if (b0 && pos < MAX_DEG) out[pos] = col;     pos += b0;
        if (b1 && pos < MAX_DEG) out[pos] = col + 1; pos += b1;
        if (b2 && pos < MAX_DEG) out[pos] = col + 2; pos += b2;
        if (b3 && pos < MAX_DEG) out[pos] = col + 3; pos += b3;
        count += __popcll(m0) + __popcll(m1) + __popcll(m2) + __popcll(m3);
    }
    int cc = (count > MAX_DEG) ? MAX_DEG : count;
    int pad = ((cc + 3) & ~3) - cc;          // 0..3 padding entries, j=0, p will be 0
    if (lane < pad) out[cc + lane] = 0;
    if (lane == 0) cnt[row] = cc;
}

// --------- fused: h = x@linW+b ; Wh = h@W_heads ; src1/dst1 ----------
// 8 nodes per block, 256 threads.
__global__ __launch_bounds__(256) void fused1_kernel(
        const float* __restrict__ x, const float* __restrict__ linW,
        const float* __restrict__ linb, const float* __restrict__ Wheads,
        const float* __restrict__ aheads, float* __restrict__ Wh,
        float* __restrict__ src1, float* __restrict__ dst1) {
    __shared__ float xs[8][128];
    __shared__ float hs[8][128];
    const int tid = threadIdx.x;
    const int i0  = blockIdx.x * 8;
    #pragma unroll
    for (int t = 0; t < 4; ++t) {
        int e = t * 256 + tid;
        xs[e >> 7][e & 127] = x[(size_t)i0 * 128 + e];
    }
    __syncthreads();
    {   // h: k = tid&127, nodes {n0, n0+2, n0+4, n0+6}
        const int k = tid & 127;
        const int n0 = tid >> 7;
        float bk = linb[k];
        float a0 = bk, a1 = bk, a2 = bk, a3 = bk;
        for (int j = 0; j < 128; ++j) {
            float w = linW[j * 128 + k];
            a0 += xs[n0][j] * w;
            a1 += xs[n0 + 2][j] * w;
            a2 += xs[n0 + 4][j] * w;
            a3 += xs[n0 + 6][j] * w;
        }
        hs[n0][k] = a0; hs[n0 + 2][k] = a1; hs[n0 + 4][k] = a2; hs[n0 + 6][k] = a3;
    }
    __syncthreads();
    // Wh: hd = wave, f = lane, all 8 nodes per thread
    const int hd = tid >> 6, f = tid & 63;
    float acc[8] = {0, 0, 0, 0, 0, 0, 0, 0};
    const float* Wp = Wheads + (size_t)hd * F_IN * F_HID + f;
    for (int j = 0; j < 128; ++j) {
        float w = Wp[j * 64];
        #pragma unroll
        for (int n = 0; n < 8; ++n) acc[n] += hs[n][j] * w;
    }
    const float as = aheads[hd * 128 + f];
    const float ad = aheads[hd * 128 + 64 + f];
    #pragma unroll
    for (int n = 0; n < 8; ++n) {
        Wh[(size_t)(i0 + n) * 256 + hd * 64 + f] = acc[n];
        float sv = acc[n] * as, dv = acc[n] * ad;
        #pragma unroll
        for (int o = 32; o > 0; o >>= 1) {
            sv += __shfl_xor(sv, o, 64);
            dv += __shfl_xor(dv, o, 64);
        }
        if (f == 0) { src1[hd * GN + i0 + n] = sv; dst1[hd * GN + i0 + n] = dv; }
    }
}

// --------- layer-1 attention: wave per (row, head); two-phase softmax ---------
__global__ void attn1_kernel(const float* __restrict__ Wh, const float* __restrict__ src,
                             const float* __restrict__ dst, const int* __restrict__ cnt,
                             const int* __restrict__ idx, float* __restrict__ hcat) {
    const int hd   = threadIdx.x >> 6;
    const int lane = threadIdx.x & 63;
    const int row  = blockIdx.x;
    const int deg  = cnt[row];
    const int* nb  = idx + (size_t)row * MAX_DEG;
    const float s_i = src[hd * GN + row];

    float e[4];
    #pragma unroll
    for (int c = 0; c < 4; ++c) {
        int t = c * 64 + lane;
        float ev = -1e30f;
        if (t < deg) {
            int j = nb[t];
            ev = s_i + dst[hd * GN + j];
            ev = (ev > 0.0f) ? ev : ALPHA * ev;
        }
        e[c] = ev;
    }
    float m = fmaxf(fmaxf(e[0], e[1]), fmaxf(e[2], e[3]));
    #pragma unroll
    for (int o = 32; o > 0; o >>= 1) m = fmaxf(m, __shfl_xor(m, o, 64));
    float l = 0.0f;
    #pragma unroll
    for (int c = 0; c < 4; ++c) { e[c] = expf(e[c] - m); l += e[c]; }
    #pragma unroll
    for (int o = 32; o > 0; o >>= 1) l += __shfl_xor(l, o, 64);

    float accA = 0.0f, accB = 0.0f;
    const float* Whh = Wh + hd * 64 + lane;
    #pragma unroll
    for (int c = 0; c < 4; ++c) {
        int base = c * 64;
        if (base >= deg) break;
        int nmax = deg - base; if (nmax > 64) nmax = 64;
        int n4 = (nmax + 3) & ~3;
        for (int t = 0; t < n4; t += 4) {
            float p0 = __shfl(e[c], t, 64);
            float p1 = __shfl(e[c], t + 1, 64);
            float p2 = __shfl(e[c], t + 2, 64);
            float p3 = __shfl(e[c], t + 3, 64);
            int j0 = nb[base + t],     j1 = nb[base + t + 1];
            int j2 = nb[base + t + 2], j3 = nb[base + t + 3];
            accA += p0 * Whh[(size_t)j0 * 256];
            accB += p1 * Whh[(size_t)j1 * 256];
            accA += p2 * Whh[(size_t)j2 * 256];
            accB += p3 * Whh[(size_t)j3 * 256];
        }
    }
    float v = (accA + accB) / l;
    v = (v > 0.0f) ? v : expm1f(v);      // elu
    hcat[(size_t)row * 256 + hd * 64 + lane] = v;
}

// --------- fused: Wh2 = hcat@W_end ; src2/dst2 ----------
// 8 nodes per block, 256 threads; wave w handles nodes {w, w+4}
__global__ __launch_bounds__(256) void fused2_kernel(
        const float* __restrict__ hcat, const float* __restrict__ Wend,
        const float* __restrict__ aend, float* __restrict__ Wh2,
        float* __restrict__ src2, float* __restrict__ dst2) {
    __shared__ float cs[8][256];
    const int tid = threadIdx.x;
    const int i0  = blockIdx.x * 8;
    #pragma unroll
    for (int t = 0; t < 8; ++t) {
        int e = t * 256 + tid;
        cs[e >> 8][e & 255] = hcat[(size_t)i0 * 256 + e];
    }
    __syncthreads();
    const int f = tid & 63;
    const int n0 = tid >> 6;     // wave = node pair {n0, n0+4}
    float a0 = 0.0f, a1 = 0.0f;
    const float* Wp = Wend + f;
    for (int j = 0; j < 256; ++j) {
        float w = Wp[j * 64];
        a0 += cs[n0][j] * w;
        a1 += cs[n0 + 4][j] * w;
    }
    const float as = aend[f];
    const float ad = aend[64 + f];
    Wh2[(size_t)(i0 + n0) * 64 + f] = a0;
    Wh2[(size_t)(i0 + n0 + 4) * 64 + f] = a1;
    float s0 = a0 * as, d0 = a0 * ad, s1 = a1 * as, d1 = a1 * ad;
    #pragma unroll
    for (int o = 32; o > 0; o >>= 1) {
        s0 += __shfl_xor(s0, o, 64); d0 += __shfl_xor(d0, o, 64);
        s1 += __shfl_xor(s1, o, 64); d1 += __shfl_xor(d1, o, 64);
    }
    if (f == 0) {
        src2[i0 + n0] = s0; dst2[i0 + n0] = d0;
        src2[i0 + n0 + 4] = s1; dst2[i0 + n0 + 4] = d1;
    }
}

// --------- layer-2 attention + elu + final row softmax; wave per row ---------
__global__ void attn2_kernel(const float* __restrict__ Wh2, const float* __restrict__ src,
                             const float* __restrict__ dst, const int* __restrict__ cnt,
                             const int* __restrict__ idx, float* __restrict__ out) {
    const int wave = threadIdx.x >> 6;
    const int lane = threadIdx.x & 63;
    const int row  = blockIdx.x * 4 + wave;
    if (row >= GN) return;
    const int deg = cnt[row];
    const int* nb = idx + (size_t)row * MAX_DEG;
    const float s_i = src[row];

    float e[4];
    #pragma unroll
    for (int c = 0; c < 4; ++c) {
        int t = c * 64 + lane;
        float ev = -1e30f;
        if (t < deg) {
            int j = nb[t];
            ev = s_i + dst[j];
            ev = (ev > 0.0f) ? ev : ALPHA * ev;
        }
        e[c] = ev;
    }
    float m = fmaxf(fmaxf(e[0], e[1]), fmaxf(e[2], e[3]));
    #pragma unroll
    for (int o = 32; o > 0; o >>= 1) m = fmaxf(m, __shfl_xor(m, o, 64));
    float l = 0.0f;
    #pragma unroll
    for (int c = 0; c < 4; ++c) { e[c] = expf(e[c] - m); l += e[c]; }
    #pragma unroll
    for (int o = 32; o > 0; o >>= 1) l += __shfl_xor(l, o, 64);

    float accA = 0.0f, accB = 0.0f;
    const float* W2 = Wh2 + lane;
    #pragma unroll
    for (int c = 0; c < 4; ++c) {
        int base = c * 64;
        if (base >= deg) break;
        int nmax = deg - base; if (nmax > 64) nmax = 64;
        int n4 = (nmax + 3) & ~3;
        for (int t = 0; t < n4; t += 4) {
            float p0 = __shfl(e[c], t, 64);
            float p1 = __shfl(e[c], t + 1, 64);
            float p2 = __shfl(e[c], t + 2, 64);
            float p3 = __shfl(e[c], t + 3, 64);
            int j0 = nb[base + t],     j1 = nb[base + t + 1];
            int j2 = nb[base + t + 2], j3 = nb[base + t + 3];
            accA += p0 * W2[(size_t)j0 * 64];
            accB += p1 * W2[(size_t)j1 * 64];
            accA += p2 * W2[(size_t)j2 * 64];
            accB += p3 * W2[(size_t)j3 * 64];
        }
    }
    float v = (accA + accB) / l;
    v = (v > 0.0f) ? v : expm1f(v);      // elu

    float mm = v;
    #pragma unroll
    for (int o = 32; o > 0; o >>= 1) mm = fmaxf(mm, __shfl_xor(mm, o, 64));
    float ee = expf(v - mm);
    float ss = ee;
    #pragma unroll
    for (int o = 32; o > 0; o >>= 1) ss += __shfl_xor(ss, o, 64);
    out[(size_t)row * F_OUT + lane] = ee / ss;
}

extern "C" void kernel_launch(void* const* d_in, const int* in_sizes, int n_in,
                              void* d_out, int out_size, void* d_ws, size_t ws_size,
                              hipStream_t stream) {
    const float* x      = (const float*)d_in[0];
    const float* adj    = (const float*)d_in[1];
    const float* lin_W  = (const float*)d_in[2];
    const float* lin_b  = (const float*)d_in[3];
    const float* Wheads = (const float*)d_in[4];
    const float* aheads = (const float*)d_in[5];
    const float* Wend   = (const float*)d_in[6];
    const float* aend   = (const float*)d_in[7];
    float* out = (float*)d_out;

    char* ws = (char*)d_ws;
    float* Wh   = (float*)(ws + OFF_WH);
    float* src1 = (float*)(ws + OFF_SRC1);
    float* dst1 = (float*)(ws + OFF_DST1);
    float* hcat = (float*)(ws + OFF_HCAT);
    float* Wh2  = (float*)(ws + OFF_WH2);
    float* src2 = (float*)(ws + OFF_SRC2);
    float* dst2 = (float*)(ws + OFF_DST2);
    int*   cnt  = (int*)(ws + OFF_CNT);
    int*   nidx = (int*)(ws + OFF_IDX);

    build_nbr_kernel<<<GN / 4, 256, 0, stream>>>(adj, cnt, nidx);
    fused1_kernel<<<GN / 8, 256, 0, stream>>>(x, lin_W, lin_b, Wheads, aheads, Wh, src1, dst1);
    attn1_kernel<<<GN, 256, 0, stream>>>(Wh, src1, dst1, cnt, nidx, hcat);
    fused2_kernel<<<GN / 8, 256, 0, stream>>>(hcat, Wend, aend, Wh2, src2, dst2);
    attn2_kernel<<<GN / 4, 256, 0, stream>>>(Wh2, src2, dst2, cnt, nidx, out);
}